// Round 3
// baseline (233.515 us; speedup 1.0000x reference)
//
#include <hip/hip_runtime.h>
#include <hip/hip_bf16.h>
#include <stdint.h>

// Problem: 3x Bahdanau attention (p/c/h heads) -> averaged softmax weights -> weighted sum of sentence.
// S=8192, H2=1024, A=2048, E=768. All inputs fp32; output fp32 [1024].
// R1: 284us. R2: 229us (gemm 71us ~ structural plateau; ~158us residue = small kernels + ~10us/node overhead).
// R3: 4 graph nodes total. No-max softmax (|e| <= sum|v| ~= 36 -> exp safe in fp32) kills the stats max-pass;
//     memsets folded into k_prep; ctxb non-atomic; transpose writes vectorized 16B/lane.

namespace {

constexpr int S = 8192;
constexpr int H = 1024;   // H2
constexpr int A = 2048;
constexpr int E = 768;

typedef __bf16 bf16x8 __attribute__((ext_vector_type(8)));
typedef float f32x4 __attribute__((ext_vector_type(4)));

__device__ __forceinline__ void gl_lds16(const void* g, void* l) {
  __builtin_amdgcn_global_load_lds(
      (const __attribute__((address_space(1))) void*)g,
      (__attribute__((address_space(3))) void*)l, 16, 0, 0);
}

// ---------- merged prep ----------
// [0,4096)      : sentence fp32 -> bf16 (len-gated: masked rows never feed anything)
// [4096,5632)   : W_sent [H][A] -> Wt [A][H] bf16, 64x64 tiles, 16B/lane writes
// [5632,5728)   : ctxb[head][a] = b_sent + b_ctx + ctx @ W_ctx (non-atomic, LDS reduce)
// [5728,5752)   : zero e_arr (gemm accumulates into it atomically)
// [5752,5753)   : zero out   (k_out accumulates into it atomically)
__global__ __launch_bounds__(256)
void k_prep(const float* __restrict__ sentence, __bf16* __restrict__ sentB,
            const float* __restrict__ Wp, const float* __restrict__ Wc_s,
            const float* __restrict__ Wh, __bf16* __restrict__ WtB,
            const float* __restrict__ ctx_p, const float* __restrict__ ctx_c,
            const float* __restrict__ ctx_h,
            const float* __restrict__ Wcx_p, const float* __restrict__ Wcx_c,
            const float* __restrict__ Wcx_h,
            const float* __restrict__ bs_p, const float* __restrict__ bs_c,
            const float* __restrict__ bs_h,
            const float* __restrict__ bc_p, const float* __restrict__ bc_c,
            const float* __restrict__ bc_h,
            float* __restrict__ ctxb, float* __restrict__ e_arr,
            float* __restrict__ outz, const int* __restrict__ length) {
  __shared__ float tile[64][65];
  __shared__ float part[4][64];
  int b = blockIdx.x;
  int t = threadIdx.x;

  if (b < 4096) {
    // ---- sentence fp32 -> bf16, 8 elems/thread; skip fully-masked row pairs ----
    int len = min(max(length[0], 0), S);
    if (b * 2 >= len) return;               // this block covers rows {2b, 2b+1}
    int g = b * 256 + t;
    const float4* s4 = (const float4*)sentence + (size_t)g * 2;
    float4 a = s4[0], c = s4[1];
    bf16x8 o;
    o[0] = (__bf16)a.x; o[1] = (__bf16)a.y; o[2] = (__bf16)a.z; o[3] = (__bf16)a.w;
    o[4] = (__bf16)c.x; o[5] = (__bf16)c.y; o[6] = (__bf16)c.z; o[7] = (__bf16)c.w;
    *((bf16x8*)sentB + g) = o;
  } else if (b < 5632) {
    // ---- W_sent [H][A] fp32 -> Wt [A][H] bf16 ----
    int r = b - 4096;                 // 512 tiles per head
    int head = r >> 9; r &= 511;
    const float* W = head == 0 ? Wp : (head == 1 ? Wc_s : Wh);
    __bf16* dst = WtB + (size_t)head * A * H;
    int a0 = (r & 31) * 64;           // 32 a-tiles
    int k0 = (r >> 5) * 64;           // 16 k-tiles
#pragma unroll
    for (int i = 0; i < 16; ++i) {
      int idx = t + i * 256;
      int rr = idx >> 6, cc = idx & 63;
      tile[cc][rr] = W[(size_t)(k0 + rr) * A + a0 + cc];   // coalesced over cc
    }
    __syncthreads();
    // write: thread -> (a_local = t>>3 (+32), k-group = t&7), 16B/lane stores
    int al = t >> 3, kg = (t & 7) * 8;
#pragma unroll
    for (int half = 0; half < 2; ++half) {
      int aa = al + half * 32;
      bf16x8 o;
#pragma unroll
      for (int j = 0; j < 8; ++j) o[j] = (__bf16)tile[aa][kg + j];
      *(bf16x8*)&dst[(size_t)(a0 + aa) * H + k0 + kg] = o;
    }
  } else if (b < 5728) {
    // ---- ctxb: 32 blocks/head, 64 a-values/block, 4 e-slices of 192 ----
    int r = b - 5632;
    int head = r >> 5; r &= 31;
    const float* ctx = head == 0 ? ctx_p : (head == 1 ? ctx_c : ctx_h);
    const float* Wc  = head == 0 ? Wcx_p : (head == 1 ? Wcx_c : Wcx_h);
    int a0 = r * 64;
    int al = t & 63, slice = t >> 6;
    int a = a0 + al;
    float s = 0.f;
    int e0 = slice * 192;
#pragma unroll 8
    for (int e = e0; e < e0 + 192; ++e) s = fmaf(ctx[e], Wc[(size_t)e * A + a], s);
    part[slice][al] = s;
    __syncthreads();
    if (t < 64) {
      const float* bs = head == 0 ? bs_p : (head == 1 ? bs_c : bs_h);
      const float* bc = head == 0 ? bc_p : (head == 1 ? bc_c : bc_h);
      ctxb[head * A + a0 + t] = part[0][t] + part[1][t] + part[2][t] + part[3][t]
                              + bs[a0 + t] + bc[a0 + t];
    }
  } else if (b < 5752) {
    // ---- zero e_arr: 3*8192 floats = 6144 float4 over 24 blocks ----
    int g = (b - 5728) * 256 + t;
    ((float4*)e_arr)[g] = (float4){0.f, 0.f, 0.f, 0.f};
  } else {
    // ---- zero out: 1024 floats = 256 float4 ----
    ((float4*)outz)[t] = (float4){0.f, 0.f, 0.f, 0.f};
  }
}

// ---------- GEMM + fused tanh*v epilogue -> e[head][s] (unchanged: at structural plateau) ----------
__global__ __launch_bounds__(256)
void k_gemm_e(const __bf16* __restrict__ sentB, const __bf16* __restrict__ WtB,
              const float* __restrict__ ctxb,
              const float* __restrict__ v_p, const float* __restrict__ v_c,
              const float* __restrict__ v_h,
              const int* __restrict__ length, float* __restrict__ e_out) {
  int m0 = blockIdx.x * 128;
  int len = length[0];
  if (m0 >= len) return;          // masked rows can never influence the softmax
  int n0 = blockIdx.y * 128;
  int head = blockIdx.z;
  const float* v  = head == 0 ? v_p : (head == 1 ? v_c : v_h);
  const __bf16* Wt = WtB + (size_t)head * A * H;
  const float* cb = ctxb + head * A;
  float* e_h = e_out + head * S;

  __shared__ __align__(16) __bf16 lsA[128 * 32];
  __shared__ __align__(16) __bf16 lsB[128 * 32];
  __shared__ float e_part[128];

  int tid = threadIdx.x;
  if (tid < 128) e_part[tid] = 0.f;

  int lane = tid & 63;
  int wave = tid >> 6;
  int wm = wave >> 1, wn = wave & 1;
  int quad = lane >> 4, l16 = lane & 15;

  f32x4 acc[4][4];
#pragma unroll
  for (int i = 0; i < 4; ++i)
#pragma unroll
    for (int j = 0; j < 4; ++j) acc[i][j] = (f32x4){0.f, 0.f, 0.f, 0.f};

  const __bf16* gA0 = sentB + (size_t)(m0 + (tid >> 2)) * H + ((tid & 3) * 8);
  const __bf16* gA1 = gA0 + (size_t)64 * H;
  const __bf16* gB0 = Wt + (size_t)(n0 + (tid >> 2)) * H + ((tid & 3) * 8);
  const __bf16* gB1 = gB0 + (size_t)64 * H;

  for (int k0 = 0; k0 < H; k0 += 32) {
    __syncthreads();
    gl_lds16(gA0 + k0, lsA + tid * 8);
    gl_lds16(gA1 + k0, lsA + 2048 + tid * 8);
    gl_lds16(gB0 + k0, lsB + tid * 8);
    gl_lds16(gB1 + k0, lsB + 2048 + tid * 8);
    __syncthreads();

    bf16x8 af[4], bfv[4];
#pragma unroll
    for (int i = 0; i < 4; ++i) {
      af[i]  = *(const bf16x8*)&lsA[(wm * 64 + i * 16 + l16) * 32 + quad * 8];
      bfv[i] = *(const bf16x8*)&lsB[(wn * 64 + i * 16 + l16) * 32 + quad * 8];
    }
#pragma unroll
    for (int i = 0; i < 4; ++i)
#pragma unroll
      for (int j = 0; j < 4; ++j)
        acc[i][j] = __builtin_amdgcn_mfma_f32_16x16x32_bf16(af[i], bfv[j], acc[i][j], 0, 0, 0);
  }

  float vj[4], cbj[4];
#pragma unroll
  for (int j = 0; j < 4; ++j) {
    int col = n0 + wn * 64 + j * 16 + l16;
    vj[j] = v[col];
    cbj[j] = cb[col];
  }
#pragma unroll
  for (int i = 0; i < 4; ++i) {
#pragma unroll
    for (int r = 0; r < 4; ++r) {
      float p = 0.f;
#pragma unroll
      for (int j = 0; j < 4; ++j) {
        float u = acc[i][j][r] + cbj[j];
        float ex = __expf(2.f * u);        // tanh = 1 - 2/(e^2x+1); inf-safe at both ends
        float th = 1.f - 2.f / (ex + 1.f);
        p = fmaf(th, vj[j], p);
      }
      p += __shfl_xor(p, 1);
      p += __shfl_xor(p, 2);
      p += __shfl_xor(p, 4);
      p += __shfl_xor(p, 8);
      if (l16 == 0) atomicAdd(&e_part[wm * 64 + i * 16 + quad * 4 + r], p);
    }
  }
  __syncthreads();
  if (tid < 128) atomicAdd(&e_h[m0 + tid], e_part[tid]);
}

// ---------- per-head sum of exp(e) over s<len, single pass (no max: |e| <= sum|v| ~ 36) ----------
__global__ __launch_bounds__(1024)
void k_sum(const float* __restrict__ e_arr, const int* __restrict__ length,
           float* __restrict__ sums) {
  int head = blockIdx.x;
  const float* e_h = e_arr + head * S;
  int len = min(max(length[0], 0), S);
  int t = threadIdx.x;
  __shared__ float red[16];

  float ss = 0.f;
  int base = t * 8;                       // 1024 threads x 8 consecutive
#pragma unroll
  for (int j = 0; j < 8; ++j) {
    int s = base + j;
    if (s < len) ss += __expf(e_h[s]);
  }
#pragma unroll
  for (int o = 32; o >= 1; o >>= 1) ss += __shfl_xor(ss, o);
  if ((t & 63) == 0) red[t >> 6] = ss;
  __syncthreads();
  if (t == 0) {
    float tot = 0.f;
#pragma unroll
    for (int i = 0; i < 16; ++i) tot += red[i];
    sums[head] = tot;
  }
}

// ---------- out[h] = sum_s w(s)*sentence[s][h]; w = mean_head exp(e)/sum ----------
__global__ void k_out(const float* __restrict__ sent, const float* __restrict__ e_arr,
                      const float* __restrict__ sums, const int* __restrict__ length,
                      float* __restrict__ out) {
  int len = min(max(length[0], 0), S);
  int r0 = blockIdx.x * 32;
  if (r0 >= len) return;
  int col = threadIdx.x * 4;
  int rend = min(r0 + 32, len);
  float i0 = 1.f / sums[0], i1 = 1.f / sums[1], i2 = 1.f / sums[2];
  float4 acc = {0.f, 0.f, 0.f, 0.f};
  for (int r = r0; r < rend; ++r) {
    float w = (__expf(e_arr[r]) * i0 +
               __expf(e_arr[S + r]) * i1 +
               __expf(e_arr[2 * S + r]) * i2) * (1.f / 3.f);
    float4 x = *(const float4*)(sent + (size_t)r * H + col);
    acc.x = fmaf(w, x.x, acc.x);
    acc.y = fmaf(w, x.y, acc.y);
    acc.z = fmaf(w, x.z, acc.z);
    acc.w = fmaf(w, x.w, acc.w);
  }
  atomicAdd(&out[col + 0], acc.x);
  atomicAdd(&out[col + 1], acc.y);
  atomicAdd(&out[col + 2], acc.z);
  atomicAdd(&out[col + 3], acc.w);
}

}  // namespace

extern "C" void kernel_launch(void* const* d_in, const int* in_sizes, int n_in,
                              void* d_out, int out_size, void* d_ws, size_t ws_size,
                              hipStream_t stream) {
  const float* sentence = (const float*)d_in[0];
  const int* length     = (const int*)d_in[1];
  const float* ctx_p = (const float*)d_in[2];
  const float* ctx_c = (const float*)d_in[3];
  const float* ctx_h = (const float*)d_in[4];
  const float* W_s[3] = {(const float*)d_in[5],  (const float*)d_in[11], (const float*)d_in[17]};
  const float* b_s[3] = {(const float*)d_in[6],  (const float*)d_in[12], (const float*)d_in[18]};
  const float* W_c[3] = {(const float*)d_in[7],  (const float*)d_in[13], (const float*)d_in[19]};
  const float* b_c[3] = {(const float*)d_in[8],  (const float*)d_in[14], (const float*)d_in[20]};
  const float* v_[3]  = {(const float*)d_in[9],  (const float*)d_in[15], (const float*)d_in[21]};
  float* out = (float*)d_out;

  // workspace layout (bytes)
  char* ws = (char*)d_ws;
  __bf16* sentB = (__bf16*)(ws);               // 8192*1024*2   = 16777216
  __bf16* WtB   = (__bf16*)(ws + 16777216);    // 3*2048*1024*2 = 12582912
  float* ctxb   = (float*)(ws + 29360128);     // 3*2048*4      = 24576
  float* e_arr  = (float*)(ws + 29384704);     // 3*8192*4      = 98304
  float* sums   = (float*)(ws + 29483008);     // 3 floats

  k_prep<<<5753, 256, 0, stream>>>(sentence, sentB,
                                   W_s[0], W_s[1], W_s[2], WtB,
                                   ctx_p, ctx_c, ctx_h,
                                   W_c[0], W_c[1], W_c[2],
                                   b_s[0], b_s[1], b_s[2],
                                   b_c[0], b_c[1], b_c[2],
                                   ctxb, e_arr, out, length);
  k_gemm_e<<<dim3(S / 128, A / 128, 3), 256, 0, stream>>>(sentB, WtB, ctxb,
                                                          v_[0], v_[1], v_[2], length, e_arr);
  k_sum<<<3, 1024, 0, stream>>>(e_arr, length, sums);
  k_out<<<S / 32, 256, 0, stream>>>(sentence, e_arr, sums, length, out);
}